// Round 11
// baseline (281.647 us; speedup 1.0000x reference)
//
#include <hip/hip_runtime.h>
#include <stdint.h>

#define N_SEQ 4096
#define MFMA16 __builtin_amdgcn_mfma_f32_16x16x32_bf16

typedef float f32x4 __attribute__((ext_vector_type(4)));
typedef float f32x2 __attribute__((ext_vector_type(2)));
typedef unsigned short u16x8 __attribute__((ext_vector_type(8)));
typedef unsigned short u16x4 __attribute__((ext_vector_type(4)));
typedef unsigned int u32x2 __attribute__((ext_vector_type(2)));
typedef __bf16 bf16x8 __attribute__((ext_vector_type(8)));

static __device__ __forceinline__ float bf2f(unsigned short u) {
    unsigned v = ((unsigned)u) << 16;
    return __builtin_bit_cast(float, v);
}

// ---------------- Kernel 0a: repack W_qkv -> bf16 fragment-ready (proven) ----------------
__global__ __launch_bounds__(256) void wrepack_kernel(
    const float* __restrict__ Wq, unsigned short* __restrict__ WqF)
{
    int idx = blockIdx.x * 256 + threadIdx.x;   // [0, 49152)
    int i = idx & 7, l = (idx >> 3) & 63, fr = idx >> 9;
    int ct = fr >> 2, ks = fr & 3;
    int k = ks * 32 + (l >> 4) * 8 + i;
    int col = ct * 16 + (l & 15);
    WqF[idx] = __builtin_bit_cast(unsigned short, (__bf16)Wq[k * 384 + col]);
}

// ---------------- Kernel 0b: repack W_proj -> bf16 fragment-ready ----------------
// WpF[(ct*4+ks)*512 + l*8 + i] = Wp[ks*32 + (l>>4)*8 + i][ct*16 + (l&15)], ct in [0,8)
__global__ __launch_bounds__(256) void wrepack2_kernel(
    const float* __restrict__ Wp, unsigned short* __restrict__ WpF)
{
    int idx = blockIdx.x * 256 + threadIdx.x;   // [0, 16384)
    int i = idx & 7, l = (idx >> 3) & 63, fr = idx >> 9;
    int ct = fr >> 2, ks = fr & 3;
    int k = ks * 32 + (l >> 4) * 8 + i;
    int col = ct * 16 + (l & 15);
    WpF[idx] = __builtin_bit_cast(unsigned short, (__bf16)Wp[k * 128 + col]);
}

// ---------------- Kernel 1: QKV projection via MFMA (round-9 proven, verbatim) ----------------
__global__ __launch_bounds__(256) void qkv_kernel(
    const float* __restrict__ x, const unsigned short* __restrict__ WqF,
    const float* __restrict__ bq, unsigned short* __restrict__ Qo,
    unsigned short* __restrict__ KFo, unsigned short* __restrict__ VFo)
{
    const int tid = threadIdx.x, lane = tid & 63, w = tid >> 6;
    const int g = lane >> 4, lo = lane & 15;
    const long r0 = (long)blockIdx.x * 32;
    const float SL = (float)(0.08838834764831845 * 1.4426950408889634);
    const f32x4 zf = {0.f, 0.f, 0.f, 0.f};

    bf16x8 xf[2][4];
    #pragma unroll
    for (int rt = 0; rt < 2; ++rt) {
        const float* xr = x + (r0 + rt * 16 + lo) * 128 + g * 8;
        #pragma unroll
        for (int ks = 0; ks < 4; ++ks) {
            f32x4 a = *(const f32x4*)&xr[ks * 32];
            f32x4 b = *(const f32x4*)&xr[ks * 32 + 4];
            bf16x8 f;
            f[0] = (__bf16)a[0]; f[1] = (__bf16)a[1]; f[2] = (__bf16)a[2]; f[3] = (__bf16)a[3];
            f[4] = (__bf16)b[0]; f[5] = (__bf16)b[1]; f[6] = (__bf16)b[2]; f[7] = (__bf16)b[3];
            xf[rt][ks] = f;
        }
    }
    f32x4 acc[2][6];
    #pragma unroll
    for (int rt = 0; rt < 2; ++rt)
        #pragma unroll
        for (int c = 0; c < 6; ++c) acc[rt][c] = zf;

    const u16x8* wp = (const u16x8*)WqF + (size_t)(w * 24) * 64 + lane;
    #pragma unroll
    for (int c = 0; c < 6; ++c)
        #pragma unroll
        for (int ks = 0; ks < 4; ++ks) {
            bf16x8 wf = __builtin_bit_cast(bf16x8, wp[(c * 4 + ks) * 64]);
            acc[0][c] = MFMA16(xf[0][ks], wf, acc[0][c], 0, 0, 0);
            acc[1][c] = MFMA16(xf[1][ks], wf, acc[1][c], 0, 0, 0);
        }

    const int bb = (int)(r0 >> 12), nn0 = (int)(r0 & 4095);
    const int bh = bb * 4 + w;
    const int t = nn0 >> 6, kvb = nn0 & 63;
    const int kk = kvb >> 5;
    #pragma unroll
    for (int c = 0; c < 6; ++c) {
        int col = (w * 6 + c) * 16 + lo;
        int rem = col - w * 96;
        int d = rem / 3, s = rem % 3;
        float bias = bq[col];
        #pragma unroll
        for (int rt = 0; rt < 2; ++rt) {
            float scale = (s == 0) ? SL : 1.0f;
            unsigned short bits[4];
            #pragma unroll
            for (int j = 0; j < 4; ++j)
                bits[j] = __builtin_bit_cast(unsigned short,
                              (__bf16)((acc[rt][c][j] + bias) * scale));
            if (s == 0) {
                long base = ((long)bh * 4096 + nn0 + rt * 16 + 4 * g) * 32 + d;
                #pragma unroll
                for (int j = 0; j < 4; ++j) Qo[base + (long)j * 32] = bits[j];
            } else if (s == 1) {
                int ct_k = (kvb >> 4) + rt;
                long base = (long)((bh * 64 + t) * 4 + ct_k) * 512
                          + ((d >> 3) * 16 + 4 * g) * 8 + (d & 7);
                #pragma unroll
                for (int j = 0; j < 4; ++j) KFo[base + j * 8] = bits[j];
            } else {
                int lg = rt * 2 + (g >> 1);
                long base = (long)(((bh * 64 + t) * 2 + kk) * 2 + (d >> 4)) * 512
                          + (lg * 16 + (d & 15)) * 8 + ((4 * g) & 7);
                u16x4 pk = {bits[0], bits[1], bits[2], bits[3]};
                *(u16x4*)&VFo[base] = pk;
            }
        }
    }
}

// ---------------- Kernel 2: flash attention, kv-split x4 (round-10 structure) ----------------
// Changes vs round 10: __launch_bounds__(256, 8) occupancy experiment;
// truncating P pack (drop +0x8000 RNE adds; bias cancels in P/Sum(P)).
__global__ __launch_bounds__(256, 8) void attn_kernel(
    const unsigned short* __restrict__ Q, const unsigned short* __restrict__ KF,
    const unsigned short* __restrict__ VF, unsigned short* __restrict__ AO)
{
    __shared__ __align__(16) unsigned char smem[19456]; // P: 4 waves x 4KB; combine overlay

    const int tid = threadIdx.x, lane = tid & 63, w = tid >> 6;
    const int g = lane >> 4, lo = lane & 15;

    // bijective XCD swizzle over 2048 blocks: each XCD owns 2 consecutive bh
    const int bid = blockIdx.x;
    const int vid = (bid & 7) * 256 + (bid >> 3);
    const int qi = vid & 127, bh = vid >> 7;
    const int q0 = qi * 32;

    bf16x8 qf[2];
    #pragma unroll
    for (int rt = 0; rt < 2; ++rt) {
        const unsigned short* p = Q + ((long)bh * 4096 + q0 + rt * 16 + lo) * 32 + g * 8;
        qf[rt] = __builtin_bit_cast(bf16x8, *(const u16x8*)p);
    }
    bf16x8 onesf;
    {
        u16x8 ou = {0x3F80,0x3F80,0x3F80,0x3F80,0x3F80,0x3F80,0x3F80,0x3F80};
        onesf = __builtin_bit_cast(bf16x8, ou);
    }
    const f32x4 zf = {0.f, 0.f, 0.f, 0.f};
    f32x4 o_[2][2] = {{zf, zf}, {zf, zf}};
    f32x4 ls[2]    = {zf, zf};

    // P LDS layout (per wave, 32x64): P[q][kv] at q*64 + (((kv>>3) ^ (q&7))*8) + (kv&7)
    int woff[2][4], roff[2][2];
    #pragma unroll
    for (int qt = 0; qt < 2; ++qt) {
        int q = lo + 16 * qt;
        #pragma unroll
        for (int ct = 0; ct < 4; ++ct) {
            int kvb = 16 * ct + 4 * g;
            woff[qt][ct] = q * 64 + (((kvb >> 3) ^ (q & 7)) * 8) + ((kvb >> 2) & 1) * 4;
        }
    }
    #pragma unroll
    for (int rt = 0; rt < 2; ++rt) {
        int q = lo + 16 * rt;
        #pragma unroll
        for (int kk = 0; kk < 2; ++kk)
            roff[rt][kk] = q * 64 + ((((4 * kk) + g) ^ (q & 7)) * 8);
    }
    unsigned short* B = (unsigned short*)(smem + w * 4096);

    const u16x8* kp = (const u16x8*)KF + ((long)bh * 64 + w * 16) * 256 + lane;
    const u16x8* vp = (const u16x8*)VF + ((long)bh * 64 + w * 16) * 256 + lane;

    u16x8 K0[4], K1[4], V0[4], V1[4];
    #pragma unroll
    for (int i = 0; i < 4; ++i) K0[i] = kp[i * 64];
    kp += 256;

#define BODY(KC, KN, VP, VC, DOPV) do {                                        \
    _Pragma("unroll")                                                          \
    for (int i = 0; i < 4; ++i) KN[i] = kp[i * 64];                            \
    kp += 256;                                                                 \
    _Pragma("unroll")                                                          \
    for (int i = 0; i < 4; ++i) VC[i] = vp[i * 64];                            \
    vp += 256;                                                                 \
    u16x8 pa_[2][2];                                                           \
    if (DOPV) {                                                                \
        _Pragma("unroll")                                                      \
        for (int kk = 0; kk < 2; ++kk)                                         \
            _Pragma("unroll")                                                  \
            for (int rt = 0; rt < 2; ++rt)                                     \
                pa_[kk][rt] = *(const u16x8*)&B[roff[rt][kk]];                 \
    }                                                                          \
    f32x4 s_[2][4];                                                            \
    _Pragma("unroll")                                                          \
    for (int ct = 0; ct < 4; ++ct) {                                           \
        bf16x8 kfr = __builtin_bit_cast(bf16x8, KC[ct]);                       \
        s_[0][ct] = MFMA16(kfr, qf[0], zf, 0, 0, 0);                           \
        s_[1][ct] = MFMA16(kfr, qf[1], zf, 0, 0, 0);                           \
    }                                                                          \
    if (DOPV) {                                                                \
        _Pragma("unroll")                                                      \
        for (int kk = 0; kk < 2; ++kk)                                         \
            _Pragma("unroll")                                                  \
            for (int rt = 0; rt < 2; ++rt) {                                   \
                bf16x8 paf = __builtin_bit_cast(bf16x8, pa_[kk][rt]);          \
                ls[rt] = MFMA16(paf, onesf, ls[rt], 0, 0, 0);                  \
                o_[rt][0] = MFMA16(paf, __builtin_bit_cast(bf16x8, VP[kk*2+0]),\
                                   o_[rt][0], 0, 0, 0);                        \
                o_[rt][1] = MFMA16(paf, __builtin_bit_cast(bf16x8, VP[kk*2+1]),\
                                   o_[rt][1], 0, 0, 0);                        \
            }                                                                  \
    }                                                                          \
    _Pragma("unroll")                                                          \
    for (int qt = 0; qt < 2; ++qt)                                             \
        _Pragma("unroll")                                                      \
        for (int ct = 0; ct < 4; ++ct) {                                       \
            unsigned b0 = __builtin_bit_cast(unsigned,                         \
                __builtin_amdgcn_exp2f(s_[qt][ct][0]));                        \
            unsigned b1 = __builtin_bit_cast(unsigned,                         \
                __builtin_amdgcn_exp2f(s_[qt][ct][1]));                        \
            unsigned b2 = __builtin_bit_cast(unsigned,                         \
                __builtin_amdgcn_exp2f(s_[qt][ct][2]));                        \
            unsigned b3 = __builtin_bit_cast(unsigned,                         \
                __builtin_amdgcn_exp2f(s_[qt][ct][3]));                        \
            u32x2 wv_;                                                         \
            wv_[0] = __builtin_amdgcn_perm(b1, b0, 0x07060302u);               \
            wv_[1] = __builtin_amdgcn_perm(b3, b2, 0x07060302u);               \
            *(u16x4*)&B[woff[qt][ct]] = __builtin_bit_cast(u16x4, wv_);        \
        }                                                                      \
    __builtin_amdgcn_sched_barrier(0);                                         \
} while (0)

    BODY(K0, K1, V1, V0, 0);                 // t = 0 of this quarter (no PV yet)
    #pragma unroll 1
    for (int t = 1; t < 15; t += 2) {
        BODY(K1, K0, V0, V1, 1);             // odd t
        BODY(K0, K1, V1, V0, 1);             // even t+1
    }
    BODY(K1, K0, V0, V1, 1);                 // t = 15 (prefetch overshoots: in-bounds ws, unused)
#undef BODY

    // final PV(15): P in B, V(15) in V1
    #pragma unroll
    for (int kk = 0; kk < 2; ++kk)
        #pragma unroll
        for (int rt = 0; rt < 2; ++rt) {
            bf16x8 paf = __builtin_bit_cast(bf16x8, *(const u16x8*)&B[roff[rt][kk]]);
            ls[rt] = MFMA16(paf, onesf, ls[rt], 0, 0, 0);
            o_[rt][0] = MFMA16(paf, __builtin_bit_cast(bf16x8, V1[kk*2+0]), o_[rt][0], 0, 0, 0);
            o_[rt][1] = MFMA16(paf, __builtin_bit_cast(bf16x8, V1[kk*2+1]), o_[rt][1], 0, 0, 0);
        }

    // ---- combine 4 kv-quarters (partials additive: no-max softmax) ----
    __syncthreads();                          // all P reads done before smem reuse
    float* comb = (float*)smem;               // [3][64][25] f32 (padded, 19.2 KB)
    if (w > 0) {
        float* myp = comb + ((w - 1) * 64 + lane) * 25;
        #pragma unroll
        for (int rt = 0; rt < 2; ++rt)
            #pragma unroll
            for (int dt = 0; dt < 2; ++dt)
                *(f32x4*)&myp[(rt * 2 + dt) * 4] = o_[rt][dt];
        *(f32x4*)&myp[16] = ls[0];
        *(f32x4*)&myp[20] = ls[1];
    }
    __syncthreads();
    if (w == 0) {
        #pragma unroll
        for (int i = 0; i < 3; ++i) {
            const float* pp = comb + (i * 64 + lane) * 25;
            #pragma unroll
            for (int rt = 0; rt < 2; ++rt) {
                #pragma unroll
                for (int dt = 0; dt < 2; ++dt)
                    o_[rt][dt] += *(const f32x4*)&pp[(rt * 2 + dt) * 4];
                ls[rt] += *(const f32x4*)&pp[16 + rt * 4];
            }
        }
        // epilogue: AO[b][n][h*32+d] bf16
        const int bb = bh >> 2, h = bh & 3;
        #pragma unroll
        for (int rt = 0; rt < 2; ++rt)
            #pragma unroll
            for (int j = 0; j < 4; ++j) {
                float rl = __builtin_amdgcn_rcpf(ls[rt][j]);
                int row = q0 + rt * 16 + 4 * g + j;
                #pragma unroll
                for (int dt = 0; dt < 2; ++dt) {
                    int e = h * 32 + lo + 16 * dt;
                    float val = o_[rt][dt][j] * rl;
                    AO[((long)bb * N_SEQ + row) * 128 + e] =
                        __builtin_bit_cast(unsigned short, (__bf16)val);
                }
            }
    }
}

// ---------------- Kernel 3: output projection via MFMA (bf16 in, fp32 out) ----------------
// Block = 32 tokens; wave w owns cols [w*32, w*32+32). Same fragment scheme as qkv.
__global__ __launch_bounds__(256) void proj_kernel(
    const unsigned short* __restrict__ AO, const unsigned short* __restrict__ WpF,
    const float* __restrict__ bp, float* __restrict__ out)
{
    const int tid = threadIdx.x, lane = tid & 63, w = tid >> 6;
    const int g = lane >> 4, lo = lane & 15;
    const long r0 = (long)blockIdx.x * 32;
    const f32x4 zf = {0.f, 0.f, 0.f, 0.f};

    // A-fragments: AO rows, already bf16
    bf16x8 xf[2][4];
    #pragma unroll
    for (int rt = 0; rt < 2; ++rt) {
        const unsigned short* xr = AO + (r0 + rt * 16 + lo) * 128 + g * 8;
        #pragma unroll
        for (int ks = 0; ks < 4; ++ks)
            xf[rt][ks] = __builtin_bit_cast(bf16x8, *(const u16x8*)&xr[ks * 32]);
    }
    f32x4 acc[2][2] = {{zf, zf}, {zf, zf}};

    const u16x8* wp = (const u16x8*)WpF + (size_t)(w * 8) * 64 + lane;
    #pragma unroll
    for (int c = 0; c < 2; ++c)
        #pragma unroll
        for (int ks = 0; ks < 4; ++ks) {
            bf16x8 wf = __builtin_bit_cast(bf16x8, wp[(c * 4 + ks) * 64]);
            acc[0][c] = MFMA16(xf[0][ks], wf, acc[0][c], 0, 0, 0);
            acc[1][c] = MFMA16(xf[1][ks], wf, acc[1][c], 0, 0, 0);
        }

    // D-layout: acc[rt][c][j] = C[row r0+rt*16+4g+j][col (w*2+c)*16+lo]
    #pragma unroll
    for (int c = 0; c < 2; ++c) {
        int col = (w * 2 + c) * 16 + lo;
        float bias = bp[col];
        #pragma unroll
        for (int rt = 0; rt < 2; ++rt) {
            long base = (r0 + rt * 16 + 4 * g) * 128 + col;
            #pragma unroll
            for (int j = 0; j < 4; ++j)
                out[base + (long)j * 128] = acc[rt][c][j] + bias;
        }
    }
}

extern "C" void kernel_launch(void* const* d_in, const int* in_sizes, int n_in,
                              void* d_out, int out_size, void* d_ws, size_t ws_size,
                              hipStream_t stream)
{
    const float* x  = (const float*)d_in[0];
    const float* Wq = (const float*)d_in[1];
    const float* bq = (const float*)d_in[2];
    const float* Wp = (const float*)d_in[3];
    const float* bp = (const float*)d_in[4];
    float* out = (float*)d_out;

    // workspace: Q (4MB) | KF (4MB) | VF (4MB) | attn-out (4MB) | WqF (96KB) | WpF (32KB)
    unsigned short* Qw   = (unsigned short*)d_ws;
    unsigned short* KFw  = Qw   + (size_t)16 * 4096 * 32;
    unsigned short* VFw  = KFw  + (size_t)16 * 4096 * 32;
    unsigned short* AOw  = VFw  + (size_t)16 * 4096 * 32;
    unsigned short* WqFw = AOw  + (size_t)16 * 4096 * 32;
    unsigned short* WpFw = WqFw + (size_t)49152;

    wrepack_kernel<<<192, 256, 0, stream>>>(Wq, WqFw);
    wrepack2_kernel<<<64, 256, 0, stream>>>(Wp, WpFw);
    qkv_kernel<<<512, 256, 0, stream>>>(x, WqFw, bq, Qw, KFw, VFw);
    attn_kernel<<<2048, 256, 0, stream>>>(Qw, KFw, VFw, AOw);
    proj_kernel<<<512, 256, 0, stream>>>(AOw, WpFw, bp, out);
}

// Round 12
// 82.412 us; speedup vs baseline: 3.4176x; 3.4176x over previous
//
#include <hip/hip_runtime.h>
#include <stdint.h>

#define N_SEQ 4096
#define MFMA16 __builtin_amdgcn_mfma_f32_16x16x32_bf16

typedef float f32x4 __attribute__((ext_vector_type(4)));
typedef float f32x2 __attribute__((ext_vector_type(2)));
typedef unsigned short u16x8 __attribute__((ext_vector_type(8)));
typedef unsigned short u16x4 __attribute__((ext_vector_type(4)));
typedef unsigned int u32x2 __attribute__((ext_vector_type(2)));
typedef __bf16 bf16x8 __attribute__((ext_vector_type(8)));

static __device__ __forceinline__ float bf2f(unsigned short u) {
    unsigned v = ((unsigned)u) << 16;
    return __builtin_bit_cast(float, v);
}

// ---------------- Kernel 0a: repack W_qkv -> bf16 fragment-ready (proven) ----------------
__global__ __launch_bounds__(256) void wrepack_kernel(
    const float* __restrict__ Wq, unsigned short* __restrict__ WqF)
{
    int idx = blockIdx.x * 256 + threadIdx.x;   // [0, 49152)
    int i = idx & 7, l = (idx >> 3) & 63, fr = idx >> 9;
    int ct = fr >> 2, ks = fr & 3;
    int k = ks * 32 + (l >> 4) * 8 + i;
    int col = ct * 16 + (l & 15);
    WqF[idx] = __builtin_bit_cast(unsigned short, (__bf16)Wq[k * 384 + col]);
}

// ---------------- Kernel 0b: repack W_proj -> bf16 fragment-ready (proven) ----------------
__global__ __launch_bounds__(256) void wrepack2_kernel(
    const float* __restrict__ Wp, unsigned short* __restrict__ WpF)
{
    int idx = blockIdx.x * 256 + threadIdx.x;   // [0, 16384)
    int i = idx & 7, l = (idx >> 3) & 63, fr = idx >> 9;
    int ct = fr >> 2, ks = fr & 3;
    int k = ks * 32 + (l >> 4) * 8 + i;
    int col = ct * 16 + (l & 15);
    WpF[idx] = __builtin_bit_cast(unsigned short, (__bf16)Wp[k * 128 + col]);
}

// ---------------- Kernel 1: QKV projection via MFMA (round-9 proven, verbatim) ----------------
__global__ __launch_bounds__(256) void qkv_kernel(
    const float* __restrict__ x, const unsigned short* __restrict__ WqF,
    const float* __restrict__ bq, unsigned short* __restrict__ Qo,
    unsigned short* __restrict__ KFo, unsigned short* __restrict__ VFo)
{
    const int tid = threadIdx.x, lane = tid & 63, w = tid >> 6;
    const int g = lane >> 4, lo = lane & 15;
    const long r0 = (long)blockIdx.x * 32;
    const float SL = (float)(0.08838834764831845 * 1.4426950408889634);
    const f32x4 zf = {0.f, 0.f, 0.f, 0.f};

    bf16x8 xf[2][4];
    #pragma unroll
    for (int rt = 0; rt < 2; ++rt) {
        const float* xr = x + (r0 + rt * 16 + lo) * 128 + g * 8;
        #pragma unroll
        for (int ks = 0; ks < 4; ++ks) {
            f32x4 a = *(const f32x4*)&xr[ks * 32];
            f32x4 b = *(const f32x4*)&xr[ks * 32 + 4];
            bf16x8 f;
            f[0] = (__bf16)a[0]; f[1] = (__bf16)a[1]; f[2] = (__bf16)a[2]; f[3] = (__bf16)a[3];
            f[4] = (__bf16)b[0]; f[5] = (__bf16)b[1]; f[6] = (__bf16)b[2]; f[7] = (__bf16)b[3];
            xf[rt][ks] = f;
        }
    }
    f32x4 acc[2][6];
    #pragma unroll
    for (int rt = 0; rt < 2; ++rt)
        #pragma unroll
        for (int c = 0; c < 6; ++c) acc[rt][c] = zf;

    const u16x8* wp = (const u16x8*)WqF + (size_t)(w * 24) * 64 + lane;
    #pragma unroll
    for (int c = 0; c < 6; ++c)
        #pragma unroll
        for (int ks = 0; ks < 4; ++ks) {
            bf16x8 wf = __builtin_bit_cast(bf16x8, wp[(c * 4 + ks) * 64]);
            acc[0][c] = MFMA16(xf[0][ks], wf, acc[0][c], 0, 0, 0);
            acc[1][c] = MFMA16(xf[1][ks], wf, acc[1][c], 0, 0, 0);
        }

    const int bb = (int)(r0 >> 12), nn0 = (int)(r0 & 4095);
    const int bh = bb * 4 + w;
    const int t = nn0 >> 6, kvb = nn0 & 63;
    const int kk = kvb >> 5;
    #pragma unroll
    for (int c = 0; c < 6; ++c) {
        int col = (w * 6 + c) * 16 + lo;
        int rem = col - w * 96;
        int d = rem / 3, s = rem % 3;
        float bias = bq[col];
        #pragma unroll
        for (int rt = 0; rt < 2; ++rt) {
            float scale = (s == 0) ? SL : 1.0f;
            unsigned short bits[4];
            #pragma unroll
            for (int j = 0; j < 4; ++j)
                bits[j] = __builtin_bit_cast(unsigned short,
                              (__bf16)((acc[rt][c][j] + bias) * scale));
            if (s == 0) {
                long base = ((long)bh * 4096 + nn0 + rt * 16 + 4 * g) * 32 + d;
                #pragma unroll
                for (int j = 0; j < 4; ++j) Qo[base + (long)j * 32] = bits[j];
            } else if (s == 1) {
                int ct_k = (kvb >> 4) + rt;
                long base = (long)((bh * 64 + t) * 4 + ct_k) * 512
                          + ((d >> 3) * 16 + 4 * g) * 8 + (d & 7);
                #pragma unroll
                for (int j = 0; j < 4; ++j) KFo[base + j * 8] = bits[j];
            } else {
                int lg = rt * 2 + (g >> 1);
                long base = (long)(((bh * 64 + t) * 2 + kk) * 2 + (d >> 4)) * 512
                          + (lg * 16 + (d & 15)) * 8 + ((4 * g) & 7);
                u16x4 pk = {bits[0], bits[1], bits[2], bits[3]};
                *(u16x4*)&VFo[base] = pk;
            }
        }
    }
}

// ---------------- Kernel 2: flash attention, kv-split x2, register-diet body ----------------
// vs round-9 proven kernel: V single-buffered (PV(t) moved same-body after softmax(t)),
// P single-buffered (same-wave DS in-order + alias-ordered write->read + sched_barrier),
// s_ ct-scoped, truncating P pack (validated round 11). Same numerics graph.
__global__ __launch_bounds__(256, 4) void attn_kernel(
    const unsigned short* __restrict__ Q, const unsigned short* __restrict__ KF,
    const unsigned short* __restrict__ VF, unsigned short* __restrict__ AO)
{
    __shared__ __align__(16) unsigned char smem[16384]; // P: 4 waves x 4KB; combine overlay 12KB

    const int tid = threadIdx.x, lane = tid & 63, w = tid >> 6;
    const int g = lane >> 4, lo = lane & 15;
    const int wq = w & 1, wh = w >> 1;

    // bijective XCD swizzle over 1024 blocks: each XCD owns 2 consecutive bh
    const int bid = blockIdx.x;
    const int vid = (bid & 7) * 128 + (bid >> 3);
    const int qi = vid & 63, bh = vid >> 6;
    const int q0 = qi * 64 + wq * 32;

    bf16x8 qf[2];
    #pragma unroll
    for (int rt = 0; rt < 2; ++rt) {
        const unsigned short* p = Q + ((long)bh * 4096 + q0 + rt * 16 + lo) * 32 + g * 8;
        qf[rt] = __builtin_bit_cast(bf16x8, *(const u16x8*)p);
    }
    bf16x8 onesf;
    {
        u16x8 ou = {0x3F80,0x3F80,0x3F80,0x3F80,0x3F80,0x3F80,0x3F80,0x3F80};
        onesf = __builtin_bit_cast(bf16x8, ou);
    }
    const f32x4 zf = {0.f, 0.f, 0.f, 0.f};
    f32x4 o_[2][2] = {{zf, zf}, {zf, zf}};
    f32x4 ls[2]    = {zf, zf};

    // P LDS layout (per wave, 32x64): P[q][kv] at q*64 + (((kv>>3) ^ (q&7))*8) + (kv&7)
    int woff[2][4], roff[2][2];
    #pragma unroll
    for (int qt = 0; qt < 2; ++qt) {
        int q = lo + 16 * qt;
        #pragma unroll
        for (int ct = 0; ct < 4; ++ct) {
            int kvb = 16 * ct + 4 * g;
            woff[qt][ct] = q * 64 + (((kvb >> 3) ^ (q & 7)) * 8) + ((kvb >> 2) & 1) * 4;
        }
    }
    #pragma unroll
    for (int rt = 0; rt < 2; ++rt) {
        int q = lo + 16 * rt;
        #pragma unroll
        for (int kk = 0; kk < 2; ++kk)
            roff[rt][kk] = q * 64 + ((((4 * kk) + g) ^ (q & 7)) * 8);
    }
    unsigned short* B = (unsigned short*)(smem + w * 4096);

    const u16x8* kp = (const u16x8*)KF + ((long)bh * 64 + wh * 32) * 256 + lane;
    const u16x8* vp = (const u16x8*)VF + ((long)bh * 64 + wh * 32) * 256 + lane;

    u16x8 K0[4], K1[4], Vb[4];
    #pragma unroll
    for (int i = 0; i < 4; ++i) K0[i] = kp[i * 64];   // K(first tile of half)
    kp += 256;

// body t: prefetch K(t+1)->KN; load V(t)->Vb; QK(t) with KC (ct-scoped softmax -> B);
// PV(t) with Vb. P write(t) precedes P read(t) in program order (same wave, same
// buffer: in-order DS HW + overlapping-region alias analysis + sched_barrier).
#define BODY(KC, KN) do {                                                      \
    _Pragma("unroll")                                                          \
    for (int i = 0; i < 4; ++i) KN[i] = kp[i * 64];                            \
    kp += 256;                                                                 \
    _Pragma("unroll")                                                          \
    for (int i = 0; i < 4; ++i) Vb[i] = vp[i * 64];                            \
    vp += 256;                                                                 \
    _Pragma("unroll")                                                          \
    for (int ct = 0; ct < 4; ++ct) {                                           \
        bf16x8 kfr = __builtin_bit_cast(bf16x8, KC[ct]);                       \
        f32x4 s0 = MFMA16(kfr, qf[0], zf, 0, 0, 0);                            \
        f32x4 s1 = MFMA16(kfr, qf[1], zf, 0, 0, 0);                            \
        unsigned a0 = __builtin_bit_cast(unsigned, __builtin_amdgcn_exp2f(s0[0]));\
        unsigned a1 = __builtin_bit_cast(unsigned, __builtin_amdgcn_exp2f(s0[1]));\
        unsigned a2 = __builtin_bit_cast(unsigned, __builtin_amdgcn_exp2f(s0[2]));\
        unsigned a3 = __builtin_bit_cast(unsigned, __builtin_amdgcn_exp2f(s0[3]));\
        u32x2 w0_;                                                             \
        w0_[0] = __builtin_amdgcn_perm(a1, a0, 0x07060302u);                   \
        w0_[1] = __builtin_amdgcn_perm(a3, a2, 0x07060302u);                   \
        *(u16x4*)&B[woff[0][ct]] = __builtin_bit_cast(u16x4, w0_);             \
        unsigned c0 = __builtin_bit_cast(unsigned, __builtin_amdgcn_exp2f(s1[0]));\
        unsigned c1 = __builtin_bit_cast(unsigned, __builtin_amdgcn_exp2f(s1[1]));\
        unsigned c2 = __builtin_bit_cast(unsigned, __builtin_amdgcn_exp2f(s1[2]));\
        unsigned c3 = __builtin_bit_cast(unsigned, __builtin_amdgcn_exp2f(s1[3]));\
        u32x2 w1_;                                                             \
        w1_[0] = __builtin_amdgcn_perm(c1, c0, 0x07060302u);                   \
        w1_[1] = __builtin_amdgcn_perm(c3, c2, 0x07060302u);                   \
        *(u16x4*)&B[woff[1][ct]] = __builtin_bit_cast(u16x4, w1_);             \
    }                                                                          \
    __builtin_amdgcn_sched_barrier(0);                                         \
    _Pragma("unroll")                                                          \
    for (int kk = 0; kk < 2; ++kk)                                             \
        _Pragma("unroll")                                                      \
        for (int rt = 0; rt < 2; ++rt) {                                       \
            bf16x8 paf = __builtin_bit_cast(bf16x8,                            \
                *(const u16x8*)&B[roff[rt][kk]]);                              \
            ls[rt] = MFMA16(paf, onesf, ls[rt], 0, 0, 0);                      \
            o_[rt][0] = MFMA16(paf, __builtin_bit_cast(bf16x8, Vb[kk*2+0]),    \
                               o_[rt][0], 0, 0, 0);                            \
            o_[rt][1] = MFMA16(paf, __builtin_bit_cast(bf16x8, Vb[kk*2+1]),    \
                               o_[rt][1], 0, 0, 0);                            \
        }                                                                      \
    __builtin_amdgcn_sched_barrier(0);                                         \
} while (0)

    #pragma unroll 1
    for (int t = 0; t < 32; t += 2) {
        BODY(K0, K1);                        // even t
        BODY(K1, K0);                        // odd t+1 (t=31 K-prefetch overshoots: in-bounds ws)
    }
#undef BODY

    // ---- combine kv-halves (partials additive: no-max softmax) ----
    __syncthreads();                      // all P reads done before smem reuse
    float* sc = (float*)smem;             // 2 pairs x 64 lanes x 24 f32 = 12 KB
    float* myp = sc + (wq * 64 + lane) * 24;
    if (wh == 1) {
        #pragma unroll
        for (int rt = 0; rt < 2; ++rt)
            #pragma unroll
            for (int dt = 0; dt < 2; ++dt)
                *(f32x4*)&myp[(rt * 2 + dt) * 4] = o_[rt][dt];
        *(f32x4*)&myp[16] = ls[0];
        *(f32x4*)&myp[20] = ls[1];
    }
    __syncthreads();
    if (wh == 0) {
        #pragma unroll
        for (int rt = 0; rt < 2; ++rt) {
            #pragma unroll
            for (int dt = 0; dt < 2; ++dt)
                o_[rt][dt] += *(const f32x4*)&myp[(rt * 2 + dt) * 4];
            ls[rt] += *(const f32x4*)&myp[16 + rt * 4];
        }
        // epilogue: AO[b][n][h*32+d] bf16
        const int bb = bh >> 2, h = bh & 3;
        #pragma unroll
        for (int rt = 0; rt < 2; ++rt)
            #pragma unroll
            for (int j = 0; j < 4; ++j) {
                float rl = __builtin_amdgcn_rcpf(ls[rt][j]);
                int row = q0 + rt * 16 + 4 * g + j;
                #pragma unroll
                for (int dt = 0; dt < 2; ++dt) {
                    int e = h * 32 + lo + 16 * dt;
                    float val = o_[rt][dt][j] * rl;
                    AO[((long)bb * N_SEQ + row) * 128 + e] =
                        __builtin_bit_cast(unsigned short, (__bf16)val);
                }
            }
    }
}

// ---------------- Kernel 3: output projection via MFMA (round-11 proven, verbatim) ----------------
__global__ __launch_bounds__(256) void proj_kernel(
    const unsigned short* __restrict__ AO, const unsigned short* __restrict__ WpF,
    const float* __restrict__ bp, float* __restrict__ out)
{
    const int tid = threadIdx.x, lane = tid & 63, w = tid >> 6;
    const int g = lane >> 4, lo = lane & 15;
    const long r0 = (long)blockIdx.x * 32;
    const f32x4 zf = {0.f, 0.f, 0.f, 0.f};

    bf16x8 xf[2][4];
    #pragma unroll
    for (int rt = 0; rt < 2; ++rt) {
        const unsigned short* xr = AO + (r0 + rt * 16 + lo) * 128 + g * 8;
        #pragma unroll
        for (int ks = 0; ks < 4; ++ks)
            xf[rt][ks] = __builtin_bit_cast(bf16x8, *(const u16x8*)&xr[ks * 32]);
    }
    f32x4 acc[2][2] = {{zf, zf}, {zf, zf}};

    const u16x8* wp = (const u16x8*)WpF + (size_t)(w * 8) * 64 + lane;
    #pragma unroll
    for (int c = 0; c < 2; ++c)
        #pragma unroll
        for (int ks = 0; ks < 4; ++ks) {
            bf16x8 wf = __builtin_bit_cast(bf16x8, wp[(c * 4 + ks) * 64]);
            acc[0][c] = MFMA16(xf[0][ks], wf, acc[0][c], 0, 0, 0);
            acc[1][c] = MFMA16(xf[1][ks], wf, acc[1][c], 0, 0, 0);
        }

    #pragma unroll
    for (int c = 0; c < 2; ++c) {
        int col = (w * 2 + c) * 16 + lo;
        float bias = bp[col];
        #pragma unroll
        for (int rt = 0; rt < 2; ++rt) {
            long base = (r0 + rt * 16 + 4 * g) * 128 + col;
            #pragma unroll
            for (int j = 0; j < 4; ++j)
                out[base + (long)j * 128] = acc[rt][c][j] + bias;
        }
    }
}

extern "C" void kernel_launch(void* const* d_in, const int* in_sizes, int n_in,
                              void* d_out, int out_size, void* d_ws, size_t ws_size,
                              hipStream_t stream)
{
    const float* x  = (const float*)d_in[0];
    const float* Wq = (const float*)d_in[1];
    const float* bq = (const float*)d_in[2];
    const float* Wp = (const float*)d_in[3];
    const float* bp = (const float*)d_in[4];
    float* out = (float*)d_out;

    // workspace: Q (4MB) | KF (4MB) | VF (4MB) | attn-out (4MB) | WqF (96KB) | WpF (32KB)
    unsigned short* Qw   = (unsigned short*)d_ws;
    unsigned short* KFw  = Qw   + (size_t)16 * 4096 * 32;
    unsigned short* VFw  = KFw  + (size_t)16 * 4096 * 32;
    unsigned short* AOw  = VFw  + (size_t)16 * 4096 * 32;
    unsigned short* WqFw = AOw  + (size_t)16 * 4096 * 32;
    unsigned short* WpFw = WqFw + (size_t)49152;

    wrepack_kernel<<<192, 256, 0, stream>>>(Wq, WqFw);
    wrepack2_kernel<<<64, 256, 0, stream>>>(Wp, WpFw);
    qkv_kernel<<<512, 256, 0, stream>>>(x, WqFw, bq, Qw, KFw, VFw);
    attn_kernel<<<1024, 256, 0, stream>>>(Qw, KFw, VFw, AOw);
    proj_kernel<<<512, 256, 0, stream>>>(AOw, WpFw, bp, out);
}

// Round 13
// 81.802 us; speedup vs baseline: 3.4430x; 1.0074x over previous
//
#include <hip/hip_runtime.h>
#include <stdint.h>

#define N_SEQ 4096
#define MFMA16 __builtin_amdgcn_mfma_f32_16x16x32_bf16

typedef float f32x4 __attribute__((ext_vector_type(4)));
typedef float f32x2 __attribute__((ext_vector_type(2)));
typedef unsigned short u16x8 __attribute__((ext_vector_type(8)));
typedef unsigned short u16x4 __attribute__((ext_vector_type(4)));
typedef unsigned int u32x2 __attribute__((ext_vector_type(2)));
typedef __bf16 bf16x8 __attribute__((ext_vector_type(8)));

static __device__ __forceinline__ float bf2f(unsigned short u) {
    unsigned v = ((unsigned)u) << 16;
    return __builtin_bit_cast(float, v);
}

// ---------------- Kernel 0a: repack W_qkv -> bf16 fragment-ready (proven) ----------------
__global__ __launch_bounds__(256) void wrepack_kernel(
    const float* __restrict__ Wq, unsigned short* __restrict__ WqF)
{
    int idx = blockIdx.x * 256 + threadIdx.x;   // [0, 49152)
    int i = idx & 7, l = (idx >> 3) & 63, fr = idx >> 9;
    int ct = fr >> 2, ks = fr & 3;
    int k = ks * 32 + (l >> 4) * 8 + i;
    int col = ct * 16 + (l & 15);
    WqF[idx] = __builtin_bit_cast(unsigned short, (__bf16)Wq[k * 384 + col]);
}

// ---------------- Kernel 0b: repack W_proj -> bf16 fragment-ready (proven) ----------------
__global__ __launch_bounds__(256) void wrepack2_kernel(
    const float* __restrict__ Wp, unsigned short* __restrict__ WpF)
{
    int idx = blockIdx.x * 256 + threadIdx.x;   // [0, 16384)
    int i = idx & 7, l = (idx >> 3) & 63, fr = idx >> 9;
    int ct = fr >> 2, ks = fr & 3;
    int k = ks * 32 + (l >> 4) * 8 + i;
    int col = ct * 16 + (l & 15);
    WpF[idx] = __builtin_bit_cast(unsigned short, (__bf16)Wp[k * 128 + col]);
}

// ---------------- Kernel 1: QKV projection via MFMA (round-9 proven, verbatim) ----------------
__global__ __launch_bounds__(256) void qkv_kernel(
    const float* __restrict__ x, const unsigned short* __restrict__ WqF,
    const float* __restrict__ bq, unsigned short* __restrict__ Qo,
    unsigned short* __restrict__ KFo, unsigned short* __restrict__ VFo)
{
    const int tid = threadIdx.x, lane = tid & 63, w = tid >> 6;
    const int g = lane >> 4, lo = lane & 15;
    const long r0 = (long)blockIdx.x * 32;
    const float SL = (float)(0.08838834764831845 * 1.4426950408889634);
    const f32x4 zf = {0.f, 0.f, 0.f, 0.f};

    bf16x8 xf[2][4];
    #pragma unroll
    for (int rt = 0; rt < 2; ++rt) {
        const float* xr = x + (r0 + rt * 16 + lo) * 128 + g * 8;
        #pragma unroll
        for (int ks = 0; ks < 4; ++ks) {
            f32x4 a = *(const f32x4*)&xr[ks * 32];
            f32x4 b = *(const f32x4*)&xr[ks * 32 + 4];
            bf16x8 f;
            f[0] = (__bf16)a[0]; f[1] = (__bf16)a[1]; f[2] = (__bf16)a[2]; f[3] = (__bf16)a[3];
            f[4] = (__bf16)b[0]; f[5] = (__bf16)b[1]; f[6] = (__bf16)b[2]; f[7] = (__bf16)b[3];
            xf[rt][ks] = f;
        }
    }
    f32x4 acc[2][6];
    #pragma unroll
    for (int rt = 0; rt < 2; ++rt)
        #pragma unroll
        for (int c = 0; c < 6; ++c) acc[rt][c] = zf;

    const u16x8* wp = (const u16x8*)WqF + (size_t)(w * 24) * 64 + lane;
    #pragma unroll
    for (int c = 0; c < 6; ++c)
        #pragma unroll
        for (int ks = 0; ks < 4; ++ks) {
            bf16x8 wf = __builtin_bit_cast(bf16x8, wp[(c * 4 + ks) * 64]);
            acc[0][c] = MFMA16(xf[0][ks], wf, acc[0][c], 0, 0, 0);
            acc[1][c] = MFMA16(xf[1][ks], wf, acc[1][c], 0, 0, 0);
        }

    const int bb = (int)(r0 >> 12), nn0 = (int)(r0 & 4095);
    const int bh = bb * 4 + w;
    const int t = nn0 >> 6, kvb = nn0 & 63;
    const int kk = kvb >> 5;
    #pragma unroll
    for (int c = 0; c < 6; ++c) {
        int col = (w * 6 + c) * 16 + lo;
        int rem = col - w * 96;
        int d = rem / 3, s = rem % 3;
        float bias = bq[col];
        #pragma unroll
        for (int rt = 0; rt < 2; ++rt) {
            float scale = (s == 0) ? SL : 1.0f;
            unsigned short bits[4];
            #pragma unroll
            for (int j = 0; j < 4; ++j)
                bits[j] = __builtin_bit_cast(unsigned short,
                              (__bf16)((acc[rt][c][j] + bias) * scale));
            if (s == 0) {
                long base = ((long)bh * 4096 + nn0 + rt * 16 + 4 * g) * 32 + d;
                #pragma unroll
                for (int j = 0; j < 4; ++j) Qo[base + (long)j * 32] = bits[j];
            } else if (s == 1) {
                int ct_k = (kvb >> 4) + rt;
                long base = (long)((bh * 64 + t) * 4 + ct_k) * 512
                          + ((d >> 3) * 16 + 4 * g) * 8 + (d & 7);
                #pragma unroll
                for (int j = 0; j < 4; ++j) KFo[base + j * 8] = bits[j];
            } else {
                int lg = rt * 2 + (g >> 1);
                long base = (long)(((bh * 64 + t) * 2 + kk) * 2 + (d >> 4)) * 512
                          + (lg * 16 + (d & 15)) * 8 + ((4 * g) & 7);
                u16x4 pk = {bits[0], bits[1], bits[2], bits[3]};
                *(u16x4*)&VFo[base] = pk;
            }
        }
    }
}

// ---------------- Kernel 2: flash attention, kv-split x2, split-phase body ----------------
// vs round-12 proven kernel (same numerics graph, same LDS order):
// BODY split into 3 fenced phases so exp2/pack of ct2,3 overlaps PV(kk0) MFMA+LDS
// latency, removing one LDS round-trip from the critical path; s_setprio(1)
// around MFMA clusters (waves are barrier-free/independent -> role diversity).
__global__ __launch_bounds__(256, 4) void attn_kernel(
    const unsigned short* __restrict__ Q, const unsigned short* __restrict__ KF,
    const unsigned short* __restrict__ VF, unsigned short* __restrict__ AO)
{
    __shared__ __align__(16) unsigned char smem[16384]; // P: 4 waves x 4KB; combine overlay 12KB

    const int tid = threadIdx.x, lane = tid & 63, w = tid >> 6;
    const int g = lane >> 4, lo = lane & 15;
    const int wq = w & 1, wh = w >> 1;

    // bijective XCD swizzle over 1024 blocks: each XCD owns 2 consecutive bh
    const int bid = blockIdx.x;
    const int vid = (bid & 7) * 128 + (bid >> 3);
    const int qi = vid & 63, bh = vid >> 6;
    const int q0 = qi * 64 + wq * 32;

    bf16x8 qf[2];
    #pragma unroll
    for (int rt = 0; rt < 2; ++rt) {
        const unsigned short* p = Q + ((long)bh * 4096 + q0 + rt * 16 + lo) * 32 + g * 8;
        qf[rt] = __builtin_bit_cast(bf16x8, *(const u16x8*)p);
    }
    bf16x8 onesf;
    {
        u16x8 ou = {0x3F80,0x3F80,0x3F80,0x3F80,0x3F80,0x3F80,0x3F80,0x3F80};
        onesf = __builtin_bit_cast(bf16x8, ou);
    }
    const f32x4 zf = {0.f, 0.f, 0.f, 0.f};
    f32x4 o_[2][2] = {{zf, zf}, {zf, zf}};
    f32x4 ls[2]    = {zf, zf};

    // P LDS layout (per wave, 32x64): P[q][kv] at q*64 + (((kv>>3) ^ (q&7))*8) + (kv&7)
    int woff[2][4], roff[2][2];
    #pragma unroll
    for (int qt = 0; qt < 2; ++qt) {
        int q = lo + 16 * qt;
        #pragma unroll
        for (int ct = 0; ct < 4; ++ct) {
            int kvb = 16 * ct + 4 * g;
            woff[qt][ct] = q * 64 + (((kvb >> 3) ^ (q & 7)) * 8) + ((kvb >> 2) & 1) * 4;
        }
    }
    #pragma unroll
    for (int rt = 0; rt < 2; ++rt) {
        int q = lo + 16 * rt;
        #pragma unroll
        for (int kk = 0; kk < 2; ++kk)
            roff[rt][kk] = q * 64 + ((((4 * kk) + g) ^ (q & 7)) * 8);
    }
    unsigned short* B = (unsigned short*)(smem + w * 4096);

    const u16x8* kp = (const u16x8*)KF + ((long)bh * 64 + wh * 32) * 256 + lane;
    const u16x8* vp = (const u16x8*)VF + ((long)bh * 64 + wh * 32) * 256 + lane;

    u16x8 K0[4], K1[4], Vb[4];
    #pragma unroll
    for (int i = 0; i < 4; ++i) K0[i] = kp[i * 64];   // K(first tile of half)
    kp += 256;

#define PACK2(S_, CT_)                                                          \
    do {                                                                        \
        unsigned a0 = __builtin_bit_cast(unsigned, __builtin_amdgcn_exp2f(S_[0][CT_][0]));\
        unsigned a1 = __builtin_bit_cast(unsigned, __builtin_amdgcn_exp2f(S_[0][CT_][1]));\
        unsigned a2 = __builtin_bit_cast(unsigned, __builtin_amdgcn_exp2f(S_[0][CT_][2]));\
        unsigned a3 = __builtin_bit_cast(unsigned, __builtin_amdgcn_exp2f(S_[0][CT_][3]));\
        u32x2 w0_;                                                              \
        w0_[0] = __builtin_amdgcn_perm(a1, a0, 0x07060302u);                    \
        w0_[1] = __builtin_amdgcn_perm(a3, a2, 0x07060302u);                    \
        *(u16x4*)&B[woff[0][CT_]] = __builtin_bit_cast(u16x4, w0_);             \
        unsigned c0 = __builtin_bit_cast(unsigned, __builtin_amdgcn_exp2f(S_[1][CT_][0]));\
        unsigned c1 = __builtin_bit_cast(unsigned, __builtin_amdgcn_exp2f(S_[1][CT_][1]));\
        unsigned c2 = __builtin_bit_cast(unsigned, __builtin_amdgcn_exp2f(S_[1][CT_][2]));\
        unsigned c3 = __builtin_bit_cast(unsigned, __builtin_amdgcn_exp2f(S_[1][CT_][3]));\
        u32x2 w1_;                                                              \
        w1_[0] = __builtin_amdgcn_perm(c1, c0, 0x07060302u);                    \
        w1_[1] = __builtin_amdgcn_perm(c3, c2, 0x07060302u);                    \
        *(u16x4*)&B[woff[1][CT_]] = __builtin_bit_cast(u16x4, w1_);             \
    } while (0)

#define PV(KK_)                                                                 \
    do {                                                                        \
        __builtin_amdgcn_s_setprio(1);                                          \
        _Pragma("unroll")                                                       \
        for (int rt = 0; rt < 2; ++rt) {                                        \
            bf16x8 paf = __builtin_bit_cast(bf16x8,                             \
                *(const u16x8*)&B[roff[rt][KK_]]);                              \
            ls[rt] = MFMA16(paf, onesf, ls[rt], 0, 0, 0);                       \
            o_[rt][0] = MFMA16(paf, __builtin_bit_cast(bf16x8, Vb[KK_*2+0]),    \
                               o_[rt][0], 0, 0, 0);                             \
            o_[rt][1] = MFMA16(paf, __builtin_bit_cast(bf16x8, Vb[KK_*2+1]),    \
                               o_[rt][1], 0, 0, 0);                             \
        }                                                                       \
        __builtin_amdgcn_s_setprio(0);                                          \
    } while (0)

// body t: prefetch K(t+1); load V(t); QK(t); phase-split softmax/PV:
//   pack ct0,1 -> fence -> PV(kk0) + pack ct2,3 -> fence -> PV(kk1) -> fence
#define BODY(KC, KN) do {                                                      \
    _Pragma("unroll")                                                          \
    for (int i = 0; i < 4; ++i) KN[i] = kp[i * 64];                            \
    kp += 256;                                                                 \
    _Pragma("unroll")                                                          \
    for (int i = 0; i < 4; ++i) Vb[i] = vp[i * 64];                            \
    vp += 256;                                                                 \
    f32x4 s_[2][4];                                                            \
    __builtin_amdgcn_s_setprio(1);                                             \
    _Pragma("unroll")                                                          \
    for (int ct = 0; ct < 4; ++ct) {                                           \
        bf16x8 kfr = __builtin_bit_cast(bf16x8, KC[ct]);                       \
        s_[0][ct] = MFMA16(kfr, qf[0], zf, 0, 0, 0);                           \
        s_[1][ct] = MFMA16(kfr, qf[1], zf, 0, 0, 0);                           \
    }                                                                          \
    __builtin_amdgcn_s_setprio(0);                                             \
    PACK2(s_, 0);                                                              \
    PACK2(s_, 1);                                                              \
    __builtin_amdgcn_sched_barrier(0);                                         \
    PV(0);                                                                     \
    PACK2(s_, 2);                                                              \
    PACK2(s_, 3);                                                              \
    __builtin_amdgcn_sched_barrier(0);                                         \
    PV(1);                                                                     \
    __builtin_amdgcn_sched_barrier(0);                                         \
} while (0)

    #pragma unroll 1
    for (int t = 0; t < 32; t += 2) {
        BODY(K0, K1);                        // even t
        BODY(K1, K0);                        // odd t+1 (t=31 K-prefetch overshoots: in-bounds ws)
    }
#undef BODY
#undef PV
#undef PACK2

    // ---- combine kv-halves (partials additive: no-max softmax) ----
    __syncthreads();                      // all P reads done before smem reuse
    float* sc = (float*)smem;             // 2 pairs x 64 lanes x 24 f32 = 12 KB
    float* myp = sc + (wq * 64 + lane) * 24;
    if (wh == 1) {
        #pragma unroll
        for (int rt = 0; rt < 2; ++rt)
            #pragma unroll
            for (int dt = 0; dt < 2; ++dt)
                *(f32x4*)&myp[(rt * 2 + dt) * 4] = o_[rt][dt];
        *(f32x4*)&myp[16] = ls[0];
        *(f32x4*)&myp[20] = ls[1];
    }
    __syncthreads();
    if (wh == 0) {
        #pragma unroll
        for (int rt = 0; rt < 2; ++rt) {
            #pragma unroll
            for (int dt = 0; dt < 2; ++dt)
                o_[rt][dt] += *(const f32x4*)&myp[(rt * 2 + dt) * 4];
            ls[rt] += *(const f32x4*)&myp[16 + rt * 4];
        }
        // epilogue: AO[b][n][h*32+d] bf16
        const int bb = bh >> 2, h = bh & 3;
        #pragma unroll
        for (int rt = 0; rt < 2; ++rt)
            #pragma unroll
            for (int j = 0; j < 4; ++j) {
                float rl = __builtin_amdgcn_rcpf(ls[rt][j]);
                int row = q0 + rt * 16 + 4 * g + j;
                #pragma unroll
                for (int dt = 0; dt < 2; ++dt) {
                    int e = h * 32 + lo + 16 * dt;
                    float val = o_[rt][dt][j] * rl;
                    AO[((long)bb * N_SEQ + row) * 128 + e] =
                        __builtin_bit_cast(unsigned short, (__bf16)val);
                }
            }
    }
}

// ---------------- Kernel 3: output projection via MFMA (round-11 proven, verbatim) ----------------
__global__ __launch_bounds__(256) void proj_kernel(
    const unsigned short* __restrict__ AO, const unsigned short* __restrict__ WpF,
    const float* __restrict__ bp, float* __restrict__ out)
{
    const int tid = threadIdx.x, lane = tid & 63, w = tid >> 6;
    const int g = lane >> 4, lo = lane & 15;
    const long r0 = (long)blockIdx.x * 32;
    const f32x4 zf = {0.f, 0.f, 0.f, 0.f};

    bf16x8 xf[2][4];
    #pragma unroll
    for (int rt = 0; rt < 2; ++rt) {
        const unsigned short* xr = AO + (r0 + rt * 16 + lo) * 128 + g * 8;
        #pragma unroll
        for (int ks = 0; ks < 4; ++ks)
            xf[rt][ks] = __builtin_bit_cast(bf16x8, *(const u16x8*)&xr[ks * 32]);
    }
    f32x4 acc[2][2] = {{zf, zf}, {zf, zf}};

    const u16x8* wp = (const u16x8*)WpF + (size_t)(w * 8) * 64 + lane;
    #pragma unroll
    for (int c = 0; c < 2; ++c)
        #pragma unroll
        for (int ks = 0; ks < 4; ++ks) {
            bf16x8 wf = __builtin_bit_cast(bf16x8, wp[(c * 4 + ks) * 64]);
            acc[0][c] = MFMA16(xf[0][ks], wf, acc[0][c], 0, 0, 0);
            acc[1][c] = MFMA16(xf[1][ks], wf, acc[1][c], 0, 0, 0);
        }

    #pragma unroll
    for (int c = 0; c < 2; ++c) {
        int col = (w * 2 + c) * 16 + lo;
        float bias = bp[col];
        #pragma unroll
        for (int rt = 0; rt < 2; ++rt) {
            long base = (r0 + rt * 16 + 4 * g) * 128 + col;
            #pragma unroll
            for (int j = 0; j < 4; ++j)
                out[base + (long)j * 128] = acc[rt][c][j] + bias;
        }
    }
}

extern "C" void kernel_launch(void* const* d_in, const int* in_sizes, int n_in,
                              void* d_out, int out_size, void* d_ws, size_t ws_size,
                              hipStream_t stream)
{
    const float* x  = (const float*)d_in[0];
    const float* Wq = (const float*)d_in[1];
    const float* bq = (const float*)d_in[2];
    const float* Wp = (const float*)d_in[3];
    const float* bp = (const float*)d_in[4];
    float* out = (float*)d_out;

    // workspace: Q (4MB) | KF (4MB) | VF (4MB) | attn-out (4MB) | WqF (96KB) | WpF (32KB)
    unsigned short* Qw   = (unsigned short*)d_ws;
    unsigned short* KFw  = Qw   + (size_t)16 * 4096 * 32;
    unsigned short* VFw  = KFw  + (size_t)16 * 4096 * 32;
    unsigned short* AOw  = VFw  + (size_t)16 * 4096 * 32;
    unsigned short* WqFw = AOw  + (size_t)16 * 4096 * 32;
    unsigned short* WpFw = WqFw + (size_t)49152;

    wrepack_kernel<<<192, 256, 0, stream>>>(Wq, WqFw);
    wrepack2_kernel<<<64, 256, 0, stream>>>(Wp, WpFw);
    qkv_kernel<<<512, 256, 0, stream>>>(x, WqFw, bq, Qw, KFw, VFw);
    attn_kernel<<<1024, 256, 0, stream>>>(Qw, KFw, VFw, AOw);
    proj_kernel<<<512, 256, 0, stream>>>(AOw, WpFw, bp, out);
}